// Round 4
// baseline (265.862 us; speedup 1.0000x reference)
//
#include <hip/hip_runtime.h>
#include <hip/hip_bf16.h>

#define HDIM 128

typedef short bf16x8 __attribute__((ext_vector_type(8)));
typedef unsigned short u16x8 __attribute__((ext_vector_type(8)));
typedef float f32x4 __attribute__((ext_vector_type(4)));

__device__ __forceinline__ short f2bf(float f) {
    __hip_bfloat16 h = __float2bfloat16(f);
    union { __hip_bfloat16 h; short s; } c; c.h = h; return c.s;
}
__device__ __forceinline__ float bf2f(unsigned short h) {
    union { unsigned u; float f; } c; c.u = ((unsigned)h) << 16; return c.f;
}
__device__ __forceinline__ bf16x8 pack8(float4 a, float4 b) {
    bf16x8 r;
    r[0] = f2bf(a.x); r[1] = f2bf(a.y); r[2] = f2bf(a.z); r[3] = f2bf(a.w);
    r[4] = f2bf(b.x); r[5] = f2bf(b.y); r[6] = f2bf(b.z); r[7] = f2bf(b.w);
    return r;
}

// ---- weight staging into MFMA B-fragment order (1024-thread versions) ----
// Fragment (nt,kt): lane l holds B[k = kt*32 + (l>>4)*8 + i][n = nt*16 + (l&15)],
// stored at wfrag[((nt*4+kt)*64 + l)*8 + i] (bf16). LDS writes are LINEAR b128.
//
// stage_T: B[k][n] = W[n][k]  (for h = z @ W^T) — per-slot 8 contiguous floats.
__device__ __forceinline__ void stage_T(const float* __restrict__ W, short* wfrag, int t) {
#pragma unroll
    for (int s = 0; s < 2; ++s) {
        int S = t + (s << 10);           // 0..2047
        int f = S >> 6, sl = S & 63;     // frag id, lane slot
        int n  = ((f >> 2) << 4) + (sl & 15);
        int k0 = ((f & 3) << 5) + ((sl >> 4) << 3);
        const float* p = W + n * HDIM + k0;
        float4 a = *(const float4*)p;
        float4 b = *(const float4*)(p + 4);
        *(bf16x8*)&wfrag[S << 3] = pack8(a, b);
    }
}
// stage_D: B[k][n] = W[k][n]  (for g1 = h1 @ wb) — per-slot 8 strided floats
// (column gather from global), LDS write stays linear b128: no LDS scatter.
__device__ __forceinline__ void stage_D(const float* __restrict__ W, short* wfrag, int t) {
#pragma unroll
    for (int s = 0; s < 2; ++s) {
        int S = t + (s << 10);
        int f = S >> 6, sl = S & 63;
        int n  = ((f >> 2) << 4) + (sl & 15);
        int k0 = ((f & 3) << 5) + ((sl >> 4) << 3);
        const float* p = W + (size_t)k0 * HDIM + n;
        bf16x8 r;
#pragma unroll
        for (int i = 0; i < 8; ++i) r[i] = f2bf(p[i * HDIM]);
        *(bf16x8*)&wfrag[S << 3] = r;
    }
}

__device__ __forceinline__ void run_gemm8(const short* wfrag, const bf16x8* a, f32x4* acc, int lane) {
#pragma unroll
    for (int kt = 0; kt < 4; ++kt) {
#pragma unroll
        for (int nt = 0; nt < 8; ++nt) {
            bf16x8 b = *(const bf16x8*)&wfrag[((((nt << 2) + kt) << 6) + lane) << 3];
            acc[nt] = __builtin_amdgcn_mfma_f32_16x16x32_bf16(a[kt], b, acc[nt], 0, 0, 0);
        }
    }
}

// ---- phase 1 (persistent, 16 waves): h1=relu(z@w1^T+b1); g1=h1@wb; h2=relu(z@w2^T+b2)
__global__ __launch_bounds__(1024, 4)
void node_phase(const float* __restrict__ z,
                const float* __restrict__ w1, const float* __restrict__ b1,
                const float* __restrict__ w2, const float* __restrict__ b2,
                const float* __restrict__ wb,
                unsigned short* __restrict__ g1, unsigned short* __restrict__ h2o,
                int N)
{
    __shared__ short wf1[16384];    // 32 KB each
    __shared__ short wf2[16384];
    __shared__ short wfb[16384];
    __shared__ short rbuf[16384];   // 32 KB: 16 waves x (16 rows x 64 cols) swizzled

    const int t = threadIdx.x;
    const int lane = t & 63, wid = t >> 6;
    const int l15 = lane & 15, kgrp = lane >> 4;
    const int g8 = lane >> 3, s8 = lane & 7;   // store-repack lane decomposition

    stage_T(w1, wf1, t);
    stage_T(w2, wf2, t);
    stage_D(wb, wfb, t);

    float bias1[8], bias2[8];
#pragma unroll
    for (int nt = 0; nt < 8; ++nt) {
        bias1[nt] = b1[nt * 16 + l15];
        bias2[nt] = b2[nt * 16 + l15];
    }
    __syncthreads();   // only barrier in the kernel

    short* rb = &rbuf[wid << 10];          // 1024 shorts (2 KB) per wave
    const int ntiles = (N + 255) >> 8;     // 256 rows per block-tile

    float4 cur[8];
    int tile = blockIdx.x;
    if (tile < ntiles) {
        int m = tile * 256 + wid * 16 + l15;
        int mc = m < N ? m : N - 1;
        const float4* zr = (const float4*)(z + (size_t)mc * HDIM);
#pragma unroll
        for (int kt = 0; kt < 4; ++kt) {
            cur[2 * kt]     = zr[kt * 8 + kgrp * 2];
            cur[2 * kt + 1] = zr[kt * 8 + kgrp * 2 + 1];
        }
    }

    for (; tile < ntiles; tile += gridDim.x) {
        // prefetch next tile's z rows
        float4 nxt[8];
        int tnext = tile + gridDim.x;
        if (tnext < ntiles) {
            int m = tnext * 256 + wid * 16 + l15;
            int mc = m < N ? m : N - 1;
            const float4* zr = (const float4*)(z + (size_t)mc * HDIM);
#pragma unroll
            for (int kt = 0; kt < 4; ++kt) {
                nxt[2 * kt]     = zr[kt * 8 + kgrp * 2];
                nxt[2 * kt + 1] = zr[kt * 8 + kgrp * 2 + 1];
            }
        }

        bf16x8 za[4];
#pragma unroll
        for (int kt = 0; kt < 4; ++kt) za[kt] = pack8(cur[2 * kt], cur[2 * kt + 1]);

        const int mwave = tile * 256 + wid * 16;

        // ---- GEMM1: h1 = relu(z @ w1^T + b1) ----
        f32x4 acc[8];
#pragma unroll
        for (int nt = 0; nt < 8; ++nt) {
            float bv = bias1[nt];
            acc[nt] = (f32x4){bv, bv, bv, bv};
        }
        run_gemm8(wf1, za, acc, lane);

        // repack h1 -> a2 A-fragments in two 64-feature half passes (in-order DS)
        bf16x8 a2[4];
#pragma unroll
        for (int p = 0; p < 2; ++p) {
#pragma unroll
            for (int nq = 0; nq < 4; ++nq) {
                int nt = p * 4 + nq;
#pragma unroll
                for (int r = 0; r < 4; ++r) {
                    float v = acc[nt][r]; v = v > 0.f ? v : 0.f;
                    int row = kgrp * 4 + r;
                    int col = nq * 16 + l15;
                    rb[row * 64 + (col ^ ((row & 7) << 3))] = f2bf(v);
                }
            }
#pragma unroll
            for (int q = 0; q < 2; ++q) {
                int col = q * 32 + kgrp * 8;
                a2[p * 2 + q] = *(const bf16x8*)&rb[l15 * 64 + (col ^ ((l15 & 7) << 3))];
            }
        }

        // ---- GEMM3: h2 = relu(z @ w2^T + b2) ----
        f32x4 acc2[8];
#pragma unroll
        for (int nt = 0; nt < 8; ++nt) {
            float bv = bias2[nt];
            acc2[nt] = (f32x4){bv, bv, bv, bv};
        }
        run_gemm8(wf2, za, acc2, lane);

        asm volatile("s_waitcnt lgkmcnt(0)" ::: "memory");  // a2 reads landed before rb reuse

        // ---- h2 store via repack halves (coalesced 16B stores) ----
#pragma unroll
        for (int p = 0; p < 2; ++p) {
#pragma unroll
            for (int nq = 0; nq < 4; ++nq) {
                int nt = p * 4 + nq;
#pragma unroll
                for (int r = 0; r < 4; ++r) {
                    float v = acc2[nt][r]; v = v > 0.f ? v : 0.f;
                    int row = kgrp * 4 + r;
                    int col = nq * 16 + l15;
                    rb[row * 64 + (col ^ ((row & 7) << 3))] = f2bf(v);
                }
            }
#pragma unroll
            for (int q = 0; q < 2; ++q) {
                int row = q * 8 + g8;
                u16x8 vv = *(const u16x8*)&rb[row * 64 + ((s8 * 8) ^ ((row & 7) << 3))];
                int m = mwave + row;
                if (m < N) *(u16x8*)&h2o[(size_t)m * HDIM + p * 64 + s8 * 8] = vv;
            }
        }

        // ---- GEMM2: g1 = h1 @ wb ----
        f32x4 accg[8];
#pragma unroll
        for (int nt = 0; nt < 8; ++nt) accg[nt] = (f32x4){0.f, 0.f, 0.f, 0.f};
        run_gemm8(wfb, a2, accg, lane);

        // ---- g1 store via repack halves ----
#pragma unroll
        for (int p = 0; p < 2; ++p) {
#pragma unroll
            for (int nq = 0; nq < 4; ++nq) {
                int nt = p * 4 + nq;
#pragma unroll
                for (int r = 0; r < 4; ++r) {
                    int row = kgrp * 4 + r;
                    int col = nq * 16 + l15;
                    rb[row * 64 + (col ^ ((row & 7) << 3))] = f2bf(accg[nt][r]);
                }
            }
#pragma unroll
            for (int q = 0; q < 2; ++q) {
                int row = q * 8 + g8;
                u16x8 vv = *(const u16x8*)&rb[row * 64 + ((s8 * 8) ^ ((row & 7) << 3))];
                int m = mwave + row;
                if (m < N) *(u16x8*)&g1[(size_t)m * HDIM + p * 64 + s8 * 8] = vv;
            }
        }

        // rotate double buffer
#pragma unroll
        for (int q = 0; q < 8; ++q) cur[q] = nxt[q];
    }
}

// ---- index dtype detection: int64 arcs have zero high words -------------
__global__ void detect_idx64(const int* __restrict__ arcs, int* __restrict__ flag)
{
    if (threadIdx.x == 0) {
        int is64 = 1;
        for (int j = 0; j < 64; ++j)
            if (arcs[2 * j + 1] != 0) { is64 = 0; break; }
        *flag = is64;
    }
}

// ---- phase 2: score[e] = dot(g1[u], h2[v]) + bb -------------------------
__global__ __launch_bounds__(256, 8)
void edge_phase(const unsigned short* __restrict__ g1,
                const unsigned short* __restrict__ h2,
                const void* __restrict__ arcs,
                const int* __restrict__ flag,
                const float* __restrict__ bb,
                float* __restrict__ out, int E)
{
    const int t = threadIdx.x;
    const int sub = t & 15;
    const int e = blockIdx.x * 16 + (t >> 4);
    const int ec = e < E ? e : (E - 1);

    long long u, v;
    if (*flag) {
        const long long* a = (const long long*)arcs;
        u = a[2 * (size_t)ec]; v = a[2 * (size_t)ec + 1];
    } else {
        const int* a = (const int*)arcs;
        u = a[2 * (size_t)ec]; v = a[2 * (size_t)ec + 1];
    }

    u16x8 av = *(const u16x8*)(g1 + (size_t)u * HDIM + sub * 8);
    u16x8 bv = *(const u16x8*)(h2 + (size_t)v * HDIM + sub * 8);
    float s = 0.f;
#pragma unroll
    for (int i = 0; i < 8; ++i) s += bf2f(av[i]) * bf2f(bv[i]);

    s += __shfl_xor(s, 8, 16);
    s += __shfl_xor(s, 4, 16);
    s += __shfl_xor(s, 2, 16);
    s += __shfl_xor(s, 1, 16);

    if (sub == 0 && e < E) out[e] = s + bb[0];
}

extern "C" void kernel_launch(void* const* d_in, const int* in_sizes, int n_in,
                              void* d_out, int out_size, void* d_ws, size_t ws_size,
                              hipStream_t stream)
{
    const float* z  = (const float*)d_in[0];
    const float* w1 = (const float*)d_in[1];
    const float* b1 = (const float*)d_in[2];
    const float* w2 = (const float*)d_in[3];
    const float* b2 = (const float*)d_in[4];
    const float* wb = (const float*)d_in[5];   // (1,128,128) -> 128x128
    const float* bb = (const float*)d_in[6];   // scalar
    const void*  arcs = d_in[7];

    const int N = in_sizes[0] / HDIM;
    const int E = in_sizes[7] / 2;

    char* ws = (char*)d_ws;
    int* flag = (int*)ws;
    unsigned short* g1 = (unsigned short*)(ws + 256);
    unsigned short* h2 = g1 + (size_t)N * HDIM;

    detect_idx64<<<1, 64, 0, stream>>>((const int*)arcs, flag);

    node_phase<<<256, 1024, 0, stream>>>(z, w1, b1, w2, b2, wb, g1, h2, N);

    int eblk = (E + 15) / 16;
    edge_phase<<<eblk, 256, 0, stream>>>(g1, h2, arcs, flag, bb, (float*)d_out, E);
}

// Round 5
// 190.541 us; speedup vs baseline: 1.3953x; 1.3953x over previous
//
#include <hip/hip_runtime.h>
#include <hip/hip_bf16.h>

#define HDIM 128

typedef short bf16x8 __attribute__((ext_vector_type(8)));
typedef short bf16x4 __attribute__((ext_vector_type(4)));
typedef unsigned short u16x8 __attribute__((ext_vector_type(8)));
typedef float f32x4 __attribute__((ext_vector_type(4)));

__device__ __forceinline__ short f2bf(float f) {
    __hip_bfloat16 h = __float2bfloat16(f);
    union { __hip_bfloat16 h; short s; } c; c.h = h; return c.s;
}
__device__ __forceinline__ float bf2f(unsigned short h) {
    union { unsigned u; float f; } c; c.u = ((unsigned)h) << 16; return c.f;
}
__device__ __forceinline__ bf16x8 pack8(float4 a, float4 b) {
    bf16x8 r;
    r[0] = f2bf(a.x); r[1] = f2bf(a.y); r[2] = f2bf(a.z); r[3] = f2bf(a.w);
    r[4] = f2bf(b.x); r[5] = f2bf(b.y); r[6] = f2bf(b.z); r[7] = f2bf(b.w);
    return r;
}

// lgkm-only barrier: orders LDS ops across waves WITHOUT draining vmcnt
// (no vmcnt(0) anywhere in the main loop; stores drain in the background).
__device__ __forceinline__ void barrier_lds() {
    asm volatile("s_waitcnt lgkmcnt(0)" ::: "memory");
    __builtin_amdgcn_s_barrier();
    __builtin_amdgcn_sched_barrier(0);
}

// ---- phase 1 (persistent, operand-swapped):
// D[feature][node]: A = weight fragments IN REGISTERS (48 VGPRs/lane),
// B = z fragments from an 8KB swizzled bf16 LDS tile (32 nodes/iter).
// Wave w owns output features [16w, 16w+16).
__global__ __launch_bounds__(512, 4)
void node_phase(const float* __restrict__ z,
                const float* __restrict__ w1, const float* __restrict__ b1,
                const float* __restrict__ w2, const float* __restrict__ b2,
                const float* __restrict__ wb,
                unsigned short* __restrict__ g1, unsigned short* __restrict__ h2o,
                int N)
{
    __shared__ short zbb[32 * 128];   // 8 KB  z tile, bf16, granule-swizzled
    __shared__ short h1x[32 * 128];   // 8 KB  h1 exchange [m][n], swizzled
    __shared__ short h2x[32 * 128];   // 8 KB  h2 staging for coalesced store
    __shared__ short g1x[32 * 128];   // 8 KB  g1 staging

    const int t = threadIdx.x;
    const int lane = t & 63, wid = t >> 6;
    const int l15 = lane & 15, kgrp = lane >> 4;
    const int feat = wid * 16 + l15;

    // ---- persistent weight A-fragments (read each matrix exactly once/block)
    bf16x8 w1f[4], w2f[4], wbf[4];
    {
        const float* w1r = w1 + (size_t)feat * HDIM;
        const float* w2r = w2 + (size_t)feat * HDIM;
#pragma unroll
        for (int kt = 0; kt < 4; ++kt) {
            int k0 = kt * 32 + kgrp * 8;
            w1f[kt] = pack8(*(const float4*)(w1r + k0), *(const float4*)(w1r + k0 + 4));
            w2f[kt] = pack8(*(const float4*)(w2r + k0), *(const float4*)(w2r + k0 + 4));
            bf16x8 r;  // A[i=n'][k=n] = wb[n][n']  (strided column gather, once)
#pragma unroll
            for (int i = 0; i < 8; ++i) r[i] = f2bf(wb[(size_t)(k0 + i) * HDIM + feat]);
            wbf[kt] = r;
        }
    }
    f32x4 bias1, bias2;
#pragma unroll
    for (int r = 0; r < 4; ++r) {
        bias1[r] = b1[wid * 16 + kgrp * 4 + r];
        bias2[r] = b2[wid * 16 + kgrp * 4 + r];
    }

    // z staging decomposition: thread t owns bf16 granule (row = t>>4, p = t&15)
    const int srow = t >> 4;              // 0..31
    const int sp   = t & 15;
    const int sg   = sp ^ (srow & 7);     // swizzle: pos p holds data granule p^(row&7)

    const int ntiles = N >> 5;            // N = 500000 is a multiple of 32

    int tile = blockIdx.x;
    if (tile < ntiles) {                  // prologue: stage tile 0
        const float* src = z + (size_t)(tile * 32 + srow) * HDIM + sg * 8;
        bf16x8 v = pack8(*(const float4*)src, *(const float4*)(src + 4));
        *(bf16x8*)&zbb[t * 8] = v;
    }
    __syncthreads();

    int prevbase = -1;
    for (; tile < ntiles; tile += gridDim.x) {
        const int base = tile * 32;
        const int nxtile = tile + (int)gridDim.x;
        const bool havenext = nxtile < ntiles;

        // ================= phase A =================
        // issue next tile's z loads early (held in regs; consumed in phase B)
        float4 zn0, zn1;
        if (havenext) {
            const float* src = z + (size_t)(nxtile * 32 + srow) * HDIM + sg * 8;
            zn0 = *(const float4*)src;
            zn1 = *(const float4*)(src + 4);
        }
        // coalesced store of previous tile's g1 (g1x sealed by last BAR2)
        if (prevbase >= 0) {
            u16x8 vv = *(const u16x8*)&g1x[srow * 128 + sp * 8];
            *(u16x8*)&g1[(size_t)(prevbase + srow) * HDIM + (sp ^ (srow & 7)) * 8] = vv;
        }

#pragma unroll
        for (int gp = 0; gp < 2; ++gp) {
            const int m = gp * 16 + l15;          // node within tile
            // z B-fragments: B[k][j=m] — 4x ds_read_b128, conflict-swizzled
            bf16x8 zf[4];
#pragma unroll
            for (int kt = 0; kt < 4; ++kt) {
                int pos = (kt * 4 + kgrp) ^ (m & 7);
                zf[kt] = *(const bf16x8*)&zbb[m * 128 + pos * 8];
            }
            f32x4 a1 = bias1, a3 = bias2;
#pragma unroll
            for (int kt = 0; kt < 4; ++kt) {
                a1 = __builtin_amdgcn_mfma_f32_16x16x32_bf16(w1f[kt], zf[kt], a1, 0, 0, 0);
                a3 = __builtin_amdgcn_mfma_f32_16x16x32_bf16(w2f[kt], zf[kt], a3, 0, 0, 0);
            }
            // D: col=lane&15=node m, row=kgrp*4+r = feature-within-wave
            const int ng = wid * 2 + (kgrp >> 1);
            const int sidx = m * 128 + ((ng ^ (m & 7)) << 3) + ((kgrp & 1) << 2);
            bf16x4 h1v, h2v;
#pragma unroll
            for (int r = 0; r < 4; ++r) {
                float x1 = a1[r] > 0.f ? a1[r] : 0.f;
                float x2 = a3[r] > 0.f ? a3[r] : 0.f;
                h1v[r] = f2bf(x1);
                h2v[r] = f2bf(x2);
            }
            *(bf16x4*)&h1x[sidx] = h1v;
            *(bf16x4*)&h2x[sidx] = h2v;
        }
        barrier_lds();   // BAR1: h1x/h2x visible; zbb reads complete

        // ================= phase B =================
#pragma unroll
        for (int gp = 0; gp < 2; ++gp) {
            const int m = gp * 16 + l15;
            f32x4 ag = (f32x4){0.f, 0.f, 0.f, 0.f};
#pragma unroll
            for (int kt = 0; kt < 4; ++kt) {
                int pos = (kt * 4 + kgrp) ^ (m & 7);
                bf16x8 bf = *(const bf16x8*)&h1x[m * 128 + pos * 8];
                ag = __builtin_amdgcn_mfma_f32_16x16x32_bf16(wbf[kt], bf, ag, 0, 0, 0);
            }
            const int ng = wid * 2 + (kgrp >> 1);
            const int sidx = m * 128 + ((ng ^ (m & 7)) << 3) + ((kgrp & 1) << 2);
            bf16x4 gv;
#pragma unroll
            for (int r = 0; r < 4; ++r) gv[r] = f2bf(ag[r]);
            *(bf16x4*)&g1x[sidx] = gv;
        }
        // coalesced h2 store (h2x sealed by BAR1)
        {
            u16x8 vv = *(const u16x8*)&h2x[srow * 128 + sp * 8];
            *(u16x8*)&h2o[(size_t)(base + srow) * HDIM + (sp ^ (srow & 7)) * 8] = vv;
        }
        // write next z tile (compiler inserts the vmcnt wait for zn0/zn1 here)
        if (havenext) {
            *(bf16x8*)&zbb[t * 8] = pack8(zn0, zn1);
        }
        prevbase = base;
        barrier_lds();   // BAR2: g1x + zbb(n+1) sealed for next phase A
    }

    // epilogue: last tile's g1
    if (prevbase >= 0) {
        u16x8 vv = *(const u16x8*)&g1x[srow * 128 + sp * 8];
        *(u16x8*)&g1[(size_t)(prevbase + srow) * HDIM + (sp ^ (srow & 7)) * 8] = vv;
    }
}

// ---- index dtype detection: int64 arcs have zero high words -------------
__global__ void detect_idx64(const int* __restrict__ arcs, int* __restrict__ flag)
{
    if (threadIdx.x == 0) {
        int is64 = 1;
        for (int j = 0; j < 64; ++j)
            if (arcs[2 * j + 1] != 0) { is64 = 0; break; }
        *flag = is64;
    }
}

// ---- phase 2: score[e] = dot(g1[u], h2[v]) + bb -------------------------
__global__ __launch_bounds__(256, 8)
void edge_phase(const unsigned short* __restrict__ g1,
                const unsigned short* __restrict__ h2,
                const void* __restrict__ arcs,
                const int* __restrict__ flag,
                const float* __restrict__ bb,
                float* __restrict__ out, int E)
{
    const int t = threadIdx.x;
    const int sub = t & 15;
    const int e = blockIdx.x * 16 + (t >> 4);
    const int ec = e < E ? e : (E - 1);

    long long u, v;
    if (*flag) {
        const long long* a = (const long long*)arcs;
        u = a[2 * (size_t)ec]; v = a[2 * (size_t)ec + 1];
    } else {
        const int* a = (const int*)arcs;
        u = a[2 * (size_t)ec]; v = a[2 * (size_t)ec + 1];
    }

    u16x8 av = *(const u16x8*)(g1 + (size_t)u * HDIM + sub * 8);
    u16x8 bv = *(const u16x8*)(h2 + (size_t)v * HDIM + sub * 8);
    float s = 0.f;
#pragma unroll
    for (int i = 0; i < 8; ++i) s += bf2f(av[i]) * bf2f(bv[i]);

    s += __shfl_xor(s, 8, 16);
    s += __shfl_xor(s, 4, 16);
    s += __shfl_xor(s, 2, 16);
    s += __shfl_xor(s, 1, 16);

    if (sub == 0 && e < E) out[e] = s + bb[0];
}

extern "C" void kernel_launch(void* const* d_in, const int* in_sizes, int n_in,
                              void* d_out, int out_size, void* d_ws, size_t ws_size,
                              hipStream_t stream)
{
    const float* z  = (const float*)d_in[0];
    const float* w1 = (const float*)d_in[1];
    const float* b1 = (const float*)d_in[2];
    const float* w2 = (const float*)d_in[3];
    const float* b2 = (const float*)d_in[4];
    const float* wb = (const float*)d_in[5];   // (1,128,128) -> 128x128
    const float* bb = (const float*)d_in[6];   // scalar
    const void*  arcs = d_in[7];

    const int N = in_sizes[0] / HDIM;
    const int E = in_sizes[7] / 2;

    char* ws = (char*)d_ws;
    int* flag = (int*)ws;
    unsigned short* g1 = (unsigned short*)(ws + 256);
    unsigned short* h2 = g1 + (size_t)N * HDIM;

    detect_idx64<<<1, 64, 0, stream>>>((const int*)arcs, flag);

    node_phase<<<512, 512, 0, stream>>>(z, w1, b1, w2, b2, wb, g1, h2, N);

    int eblk = (E + 15) / 16;
    edge_phase<<<eblk, 256, 0, stream>>>(g1, h2, arcs, flag, bb, (float*)d_out, E);
}

// Round 6
// 186.927 us; speedup vs baseline: 1.4223x; 1.0193x over previous
//
#include <hip/hip_runtime.h>
#include <hip/hip_bf16.h>

#define HDIM 128

typedef short bf16x8 __attribute__((ext_vector_type(8)));
typedef short bf16x4 __attribute__((ext_vector_type(4)));
typedef unsigned short u16x8 __attribute__((ext_vector_type(8)));
typedef float f32x4 __attribute__((ext_vector_type(4)));

__device__ __forceinline__ short f2bf(float f) {
    __hip_bfloat16 h = __float2bfloat16(f);
    union { __hip_bfloat16 h; short s; } c; c.h = h; return c.s;
}
__device__ __forceinline__ float bf2f(unsigned short h) {
    union { unsigned u; float f; } c; c.u = ((unsigned)h) << 16; return c.f;
}
__device__ __forceinline__ bf16x8 pack8(float4 a, float4 b) {
    bf16x8 r;
    r[0] = f2bf(a.x); r[1] = f2bf(a.y); r[2] = f2bf(a.z); r[3] = f2bf(a.w);
    r[4] = f2bf(b.x); r[5] = f2bf(b.y); r[6] = f2bf(b.z); r[7] = f2bf(b.w);
    return r;
}

// lgkm-only barrier: orders LDS ops across waves WITHOUT draining vmcnt.
__device__ __forceinline__ void barrier_lds() {
    asm volatile("s_waitcnt lgkmcnt(0)" ::: "memory");
    __builtin_amdgcn_s_barrier();
    __builtin_amdgcn_sched_barrier(0);
}

// ---- phase 1 (persistent, operand-swapped, 1-barrier software pipeline):
// D[feature][node]: A = weight fragments in registers (48 VGPRs/lane),
// B = z / h1 fragments from double-buffered swizzled LDS tiles (32 nodes/iter).
// Stage schedule at iter i:  A: h1,h2(T_i)   B: g1(T_{i-1})
//   stores: h2(T_{i-1}), g1(T_{i-2})   stage: z(T_{i+1})   then ONE barrier.
__global__ __launch_bounds__(512, 4)
void node_phase(const float* __restrict__ z,
                const float* __restrict__ w1, const float* __restrict__ b1,
                const float* __restrict__ w2, const float* __restrict__ b2,
                const float* __restrict__ wb,
                unsigned short* __restrict__ g1, unsigned short* __restrict__ h2o,
                int N)
{
    __shared__ short zbb[2][4096];   // 8 KB each side: z tile, bf16, granule-swizzled
    __shared__ short h1x[2][4096];   // h1 exchange
    __shared__ short h2x[2][4096];   // h2 store staging
    __shared__ short g1x[2][4096];   // g1 store staging

    const int t = threadIdx.x;
    const int lane = t & 63, wid = t >> 6;
    const int l15 = lane & 15, kgrp = lane >> 4;
    const int feat = wid * 16 + l15;

    // persistent weight A-fragments (each matrix read exactly once per block)
    bf16x8 w1f[4], w2f[4], wbf[4];
    {
        const float* w1r = w1 + (size_t)feat * HDIM;
        const float* w2r = w2 + (size_t)feat * HDIM;
#pragma unroll
        for (int kt = 0; kt < 4; ++kt) {
            int k0 = kt * 32 + kgrp * 8;
            w1f[kt] = pack8(*(const float4*)(w1r + k0), *(const float4*)(w1r + k0 + 4));
            w2f[kt] = pack8(*(const float4*)(w2r + k0), *(const float4*)(w2r + k0 + 4));
            bf16x8 r;  // A[i][k=n] = wb[n][feat] column gather (once per block)
#pragma unroll
            for (int i = 0; i < 8; ++i) r[i] = f2bf(wb[(size_t)(k0 + i) * HDIM + feat]);
            wbf[kt] = r;
        }
    }
    f32x4 bias1, bias2;
#pragma unroll
    for (int r = 0; r < 4; ++r) {
        bias1[r] = b1[wid * 16 + kgrp * 4 + r];
        bias2[r] = b2[wid * 16 + kgrp * 4 + r];
    }

    // z/store lane decomposition: thread t owns granule (row=t>>4, pos=t&15)
    const int srow = t >> 4;              // 0..31
    const int sp   = t & 15;
    const int sg   = sp ^ (srow & 7);     // swizzle: pos p holds data granule p^(row&7)

    const int ntiles = (N + 31) >> 5;
    const int myTiles = (ntiles > (int)blockIdx.x)
                      ? ((ntiles - 1 - (int)blockIdx.x) / (int)gridDim.x + 1) : 0;
    const int nit = myTiles + 2;
    const int ng = wid * 2 + (kgrp >> 1);   // D-store granule index

    // prologue: stage tile T_0 into zbb[0]
    if (myTiles > 0) {
        int row = (int)blockIdx.x * 32 + srow;
        int rc = row < N ? row : N - 1;
        const float* src = z + (size_t)rc * HDIM + sg * 8;
        *(bf16x8*)&zbb[0][t * 8] = pack8(*(const float4*)src, *(const float4*)(src + 4));
    }
    __syncthreads();

    for (int i = 0; i < nit; ++i) {
        const int cur = i & 1, prv = cur ^ 1;
        const int tvA = (int)blockIdx.x + i * (int)gridDim.x;
        const bool vA = (i < myTiles);
        const bool vB = (i >= 1) && (i - 1 < myTiles);
        const bool vG = (i >= 2) && (i - 2 < myTiles);
        const bool vP = (i + 1 < myTiles);

        // 1. issue z loads for T_{i+1} (consumed at step 6 -> ~full iter of cover)
        float4 zn0, zn1;
        if (vP) {
            int row = (tvA + (int)gridDim.x) * 32 + srow;
            int rc = row < N ? row : N - 1;
            const float* src = z + (size_t)rc * HDIM + sg * 8;
            zn0 = *(const float4*)src;
            zn1 = *(const float4*)(src + 4);
        }
        // 2. g1 store for T_{i-2}
        if (vG) {
            int row = (tvA - 2 * (int)gridDim.x) * 32 + srow;
            u16x8 vv = *(const u16x8*)&g1x[prv][srow * 128 + sp * 8];
            if (row < N) *(u16x8*)&g1[(size_t)row * HDIM + (sp ^ (srow & 7)) * 8] = vv;
        }
        // 3. h2 store for T_{i-1}
        if (vB) {
            int row = (tvA - (int)gridDim.x) * 32 + srow;
            u16x8 vv = *(const u16x8*)&h2x[prv][srow * 128 + sp * 8];
            if (row < N) *(u16x8*)&h2o[(size_t)row * HDIM + (sp ^ (srow & 7)) * 8] = vv;
        }
        // 4. phase A: h1,h2 for T_i from zbb[cur]
        if (vA) {
#pragma unroll
            for (int gp = 0; gp < 2; ++gp) {
                const int m = gp * 16 + l15;
                bf16x8 zf[4];
#pragma unroll
                for (int kt = 0; kt < 4; ++kt) {
                    int pos = (kt * 4 + kgrp) ^ (m & 7);
                    zf[kt] = *(const bf16x8*)&zbb[cur][m * 128 + pos * 8];
                }
                f32x4 a1 = bias1, a3 = bias2;
#pragma unroll
                for (int kt = 0; kt < 4; ++kt) {
                    a1 = __builtin_amdgcn_mfma_f32_16x16x32_bf16(w1f[kt], zf[kt], a1, 0, 0, 0);
                    a3 = __builtin_amdgcn_mfma_f32_16x16x32_bf16(w2f[kt], zf[kt], a3, 0, 0, 0);
                }
                const int sidx = m * 128 + ((ng ^ (m & 7)) << 3) + ((kgrp & 1) << 2);
                bf16x4 h1v, h2v;
#pragma unroll
                for (int r = 0; r < 4; ++r) {
                    float x1 = a1[r] > 0.f ? a1[r] : 0.f;
                    float x2 = a3[r] > 0.f ? a3[r] : 0.f;
                    h1v[r] = f2bf(x1);
                    h2v[r] = f2bf(x2);
                }
                *(bf16x4*)&h1x[cur][sidx] = h1v;
                *(bf16x4*)&h2x[cur][sidx] = h2v;
            }
        }
        // 5. phase B: g1 for T_{i-1} from h1x[prv]
        if (vB) {
#pragma unroll
            for (int gp = 0; gp < 2; ++gp) {
                const int m = gp * 16 + l15;
                f32x4 ag = (f32x4){0.f, 0.f, 0.f, 0.f};
#pragma unroll
                for (int kt = 0; kt < 4; ++kt) {
                    int pos = (kt * 4 + kgrp) ^ (m & 7);
                    bf16x8 bf = *(const bf16x8*)&h1x[prv][m * 128 + pos * 8];
                    ag = __builtin_amdgcn_mfma_f32_16x16x32_bf16(wbf[kt], bf, ag, 0, 0, 0);
                }
                const int sidx = m * 128 + ((ng ^ (m & 7)) << 3) + ((kgrp & 1) << 2);
                bf16x4 gv;
#pragma unroll
                for (int r = 0; r < 4; ++r) gv[r] = f2bf(ag[r]);
                *(bf16x4*)&g1x[cur][sidx] = gv;
            }
        }
        // 6. write next z tile into zbb[prv] (vmcnt waits only on step-1 loads)
        if (vP) {
            *(bf16x8*)&zbb[prv][t * 8] = pack8(zn0, zn1);
        }
        // 7. ONE barrier seals zbb[prv], h1x/h2x/g1x[cur] for the next iteration
        barrier_lds();
    }
}

// ---- index dtype detection: int64 arcs have zero high words -------------
__global__ void detect_idx64(const int* __restrict__ arcs, int* __restrict__ flag)
{
    if (threadIdx.x == 0) {
        int is64 = 1;
        for (int j = 0; j < 64; ++j)
            if (arcs[2 * j + 1] != 0) { is64 = 0; break; }
        *flag = is64;
    }
}

// ---- phase 2: score[e] = dot(g1[u], h2[v]) + bb -------------------------
__global__ __launch_bounds__(256, 8)
void edge_phase(const unsigned short* __restrict__ g1,
                const unsigned short* __restrict__ h2,
                const void* __restrict__ arcs,
                const int* __restrict__ flag,
                const float* __restrict__ bb,
                float* __restrict__ out, int E)
{
    const int t = threadIdx.x;
    const int sub = t & 15;
    const int e = blockIdx.x * 16 + (t >> 4);
    const int ec = e < E ? e : (E - 1);

    long long u, v;
    if (*flag) {
        const long long* a = (const long long*)arcs;
        u = a[2 * (size_t)ec]; v = a[2 * (size_t)ec + 1];
    } else {
        const int* a = (const int*)arcs;
        u = a[2 * (size_t)ec]; v = a[2 * (size_t)ec + 1];
    }

    u16x8 av = *(const u16x8*)(g1 + (size_t)u * HDIM + sub * 8);
    u16x8 bv = *(const u16x8*)(h2 + (size_t)v * HDIM + sub * 8);
    float s = 0.f;
#pragma unroll
    for (int i = 0; i < 8; ++i) s += bf2f(av[i]) * bf2f(bv[i]);

    s += __shfl_xor(s, 8, 16);
    s += __shfl_xor(s, 4, 16);
    s += __shfl_xor(s, 2, 16);
    s += __shfl_xor(s, 1, 16);

    if (sub == 0 && e < E) out[e] = s + bb[0];
}

extern "C" void kernel_launch(void* const* d_in, const int* in_sizes, int n_in,
                              void* d_out, int out_size, void* d_ws, size_t ws_size,
                              hipStream_t stream)
{
    const float* z  = (const float*)d_in[0];
    const float* w1 = (const float*)d_in[1];
    const float* b1 = (const float*)d_in[2];
    const float* w2 = (const float*)d_in[3];
    const float* b2 = (const float*)d_in[4];
    const float* wb = (const float*)d_in[5];   // (1,128,128) -> 128x128
    const float* bb = (const float*)d_in[6];   // scalar
    const void*  arcs = d_in[7];

    const int N = in_sizes[0] / HDIM;
    const int E = in_sizes[7] / 2;

    char* ws = (char*)d_ws;
    int* flag = (int*)ws;
    unsigned short* g1 = (unsigned short*)(ws + 256);
    unsigned short* h2 = g1 + (size_t)N * HDIM;

    detect_idx64<<<1, 64, 0, stream>>>((const int*)arcs, flag);

    node_phase<<<512, 512, 0, stream>>>(z, w1, b1, w2, b2, wb, g1, h2, N);

    int eblk = (E + 15) / 16;
    edge_phase<<<eblk, 256, 0, stream>>>(g1, h2, arcs, flag, bb, (float*)d_out, E);
}